// Round 11
// baseline (279.517 us; speedup 1.0000x reference)
//
#include <hip/hip_runtime.h>
#include <hip/hip_bf16.h>

typedef __hip_bfloat16 bf16;
typedef short bf16x8 __attribute__((ext_vector_type(8)));   // 8 bf16 = 4 VGPRs
typedef float f32x4 __attribute__((ext_vector_type(4)));    // C/D frag

#define D_MODEL 1024
#define SEQ     2048
#define NHEAD   16
#define DHEAD   64
#define BATCH   2
#define MROWS   (BATCH*SEQ)   // 4096
#define LOG2E   1.4426950408889634f

// async global->LDS, 16B per lane (m97 lever). Dest = wave-uniform base +
// lane*16 (m104/m108) — all call sites satisfy this.
__device__ __forceinline__ void lds_dma16(const bf16* g, bf16* l) {
  __builtin_amdgcn_global_load_lds(
      (const __attribute__((address_space(1))) void*)g,
      (__attribute__((address_space(3))) void*)l, 16, 0, 0);
}

__device__ __forceinline__ uint4 pack8_f32(const float4 x0, const float4 x1) {
  union { uint4 q; bf16 h[8]; } pk;
  pk.h[0]=__float2bfloat16(x0.x); pk.h[1]=__float2bfloat16(x0.y);
  pk.h[2]=__float2bfloat16(x0.z); pk.h[3]=__float2bfloat16(x0.w);
  pk.h[4]=__float2bfloat16(x1.x); pk.h[5]=__float2bfloat16(x1.y);
  pk.h[6]=__float2bfloat16(x1.z); pk.h[7]=__float2bfloat16(x1.w);
  return pk.q;
}

// ---------------------------------------------------------------------------
// Convert 4 WEIGHT matrices fp32 -> bf16. grid (128,4). Activations are now
// converted inline in gemm3 (round-11) — this removes ~114 MB of convert
// streaming (~17 µs). Round 7's inline-convert failure (FETCH 200MB) was
// cross-XCD A re-reads; the round-9/10 XCD rectangle swizzle makes the 8
// sharers of each A panel co-resident on one XCD -> L2 absorbs re-reads.
// ---------------------------------------------------------------------------
__global__ __launch_bounds__(256) void convert4(
    const float* s0, const float* s1, const float* s2, const float* s3,
    bf16* d0, bf16* d1, bf16* d2, bf16* d3)
{
  const float* S[4] = {s0,s1,s2,s3};
  bf16*        D[4] = {d0,d1,d2,d3};
  const int z = blockIdx.y;
  const int n8 = D_MODEL*D_MODEL/8;
  for (int i = blockIdx.x*256 + threadIdx.x; i < n8; i += 128*256) {
    float4 a = ((const float4*)S[z])[2*i];
    float4 b = ((const float4*)S[z])[2*i+1];
    ((uint4*)D[z])[i] = pack8_f32(a, b);
  }
}

// ---------------------------------------------------------------------------
// QKV GEMM. 128x128 tile, 512 threads / 8 waves (4wm x 2wn), per-wave 32x64.
// XCD rectangular swizzle (round-9 verified). 48 KB LDS (round-10 verified).
// ROUND-11: fp32 ACTIVATIONS read directly — A reg-staged as 4x float4,
// packed to bf16 at the ds_write. Per-iter vmcnt ledger: entering kt the
// queue is [rA(kt)x4 oldest, W(kt)x2]; ds_write's compiler wait = vmcnt(2);
// after issuing rA(kt+1)x4 + W-DMA(kt+1)x2 the explicit wait vmcnt(6)
// drains only W(kt). Next tile's 6 loads stay in flight across compute.
// ---------------------------------------------------------------------------
__global__ __launch_bounds__(512) void gemm3_dma(
    const float* A0, const float* A1, const float* A2,
    const bf16* W0, const bf16* W1, const bf16* W2,
    const float* B0, const float* B1, const float* B2,
    bf16* C0, bf16* C1, bf16* VpT)
{
  __shared__ __align__(16) bf16 As[8*128*8];      // 16 KB single-buffer
  __shared__ __align__(16) bf16 Ws[2][8*128*8];   // 2 x 16 KB dbuf
  const int z = blockIdx.z;
  const float* A = (z == 0) ? A0 : (z == 1) ? A1 : A2;
  const bf16*  W = (z == 0) ? W0 : (z == 1) ? W1 : W2;
  const float* Bv = (z == 0) ? B0 : (z == 1) ? B1 : B2;
  const bool swapped = (z < 2);
  const int K = D_MODEL, N = D_MODEL;
  const int tid  = threadIdx.x;
  const int lane = tid & 63, wave = tid >> 6;     // wave 0..7
  const int wm   = wave >> 1, wn = wave & 1;      // 4 x 2
  const int quad = lane >> 4, l16 = lane & 15;

  // XCD-aware rectangular remap (bijective within each z-plane of 256):
  // each XCD owns a 4x8 (y,x) rectangle; the 8 bx-blocks sharing an A
  // row-panel are co-resident on ONE XCD -> fp32 A re-reads are L2 hits.
  const int l    = blockIdx.x + (blockIdx.y << 3);  // hw linear, 0..255
  const int xcd  = l & 7, slot = l >> 3;
  const int bx   = slot & 7;
  const int by   = (xcd << 2) + (slot >> 3);
  const int row0 = by * 128, col0 = bx * 128;

  // A reg-staging slots: thread handles chunks (g_, r_) and (g_+4, r_)
  const int r_ = tid & 127, g_ = tid >> 7;        // g_ in 0..3
  const float* Arow = A + (size_t)(row0 + r_)*K;

  const f32x4 zero = {0.f, 0.f, 0.f, 0.f};
  f32x4 acc[2][4];
  #pragma unroll
  for (int i = 0; i < 2; ++i)
    #pragma unroll
    for (int j = 0; j < 4; ++j) acc[i][j] = zero;

  // prologue: rA(0) FIRST (oldest in vmcnt queue), then W(0) DMA
  float4 rA0 = *(const float4*)(Arow + g_*8);
  float4 rA1 = *(const float4*)(Arow + g_*8 + 4);
  float4 rA2 = *(const float4*)(Arow + (4+g_)*8);
  float4 rA3 = *(const float4*)(Arow + (4+g_)*8 + 4);
  #pragma unroll
  for (int t = 0; t < 2; ++t) {
    int s = t*512 + tid;
    int g = s >> 7, r = s & 127;
    lds_dma16(W + (size_t)(col0 + r)*K + g*8, &Ws[0][s*8]);
  }

  const int NT = K / 64;   // 16
  for (int kt = 0; kt < NT; ++kt) {
    const int cur = kt & 1;
    __builtin_amdgcn_s_barrier();            // (A) all done compute(kt-1)
    __builtin_amdgcn_sched_barrier(0);
    // ds_write A(kt): compiler waits vmcnt(2) (rA(kt) oldest; W(kt) newer)
    *(uint4*)&As[(g_*128 + r_)*8]     = pack8_f32(rA0, rA1);
    *(uint4*)&As[((4+g_)*128 + r_)*8] = pack8_f32(rA2, rA3);
    if (kt + 1 < NT) {
      const int k0n = (kt + 1) * 64;
      rA0 = *(const float4*)(Arow + k0n + g_*8);
      rA1 = *(const float4*)(Arow + k0n + g_*8 + 4);
      rA2 = *(const float4*)(Arow + k0n + (4+g_)*8);
      rA3 = *(const float4*)(Arow + k0n + (4+g_)*8 + 4);
      #pragma unroll
      for (int t = 0; t < 2; ++t) {
        int s = t*512 + tid;
        int g = s >> 7, r = s & 127;
        lds_dma16(W + (size_t)(col0 + r)*K + k0n + g*8, &Ws[cur^1][s*8]);
      }
      // outstanding: [W(kt)x2, rA(kt+1)x4, W(kt+1)x2] -> drain W(kt) only
      asm volatile("s_waitcnt vmcnt(6)" ::: "memory");
    } else {
      asm volatile("s_waitcnt vmcnt(0)" ::: "memory");  // final drain
    }
    __builtin_amdgcn_sched_barrier(0);
    asm volatile("s_waitcnt lgkmcnt(0)" ::: "memory");  // A ds_writes done
    __builtin_amdgcn_sched_barrier(0);
    __builtin_amdgcn_s_barrier();            // (B) As + Ws[cur] ready
    __builtin_amdgcn_sched_barrier(0);

    #pragma unroll
    for (int ks = 0; ks < 2; ++ks) {
      bf16x8 af[2], wf[4];
      #pragma unroll
      for (int mt = 0; mt < 2; ++mt)
        af[mt] = *(const bf16x8*)&As[((ks*4 + quad)*128 + wm*32 + mt*16 + l16)*8];
      #pragma unroll
      for (int nt = 0; nt < 4; ++nt)
        wf[nt] = *(const bf16x8*)&Ws[cur][((ks*4 + quad)*128 + wn*64 + nt*16 + l16)*8];
      __builtin_amdgcn_s_setprio(1);
      if (swapped) {
        #pragma unroll
        for (int mt = 0; mt < 2; ++mt)
          #pragma unroll
          for (int nt = 0; nt < 4; ++nt)
            acc[mt][nt] = __builtin_amdgcn_mfma_f32_16x16x32_bf16(wf[nt], af[mt], acc[mt][nt], 0, 0, 0);
      } else {
        #pragma unroll
        for (int mt = 0; mt < 2; ++mt)
          #pragma unroll
          for (int nt = 0; nt < 4; ++nt)
            acc[mt][nt] = __builtin_amdgcn_mfma_f32_16x16x32_bf16(af[mt], wf[nt], acc[mt][nt], 0, 0, 0);
      }
      __builtin_amdgcn_s_setprio(0);
    }
    // pin compute (ds_reads + MFMAs) before next iteration's bar(A)
    __builtin_amdgcn_sched_barrier(0);
  }

  if (swapped) {
    bf16* C = (z == 0) ? C0 : C1;
    const float scale = (z == 0) ? 0.125f*LOG2E : 1.0f;
    // D[c][m]: lane holds cols c0..c0+3 of row r -> 8B packed stores
    #pragma unroll
    for (int mt = 0; mt < 2; ++mt) {
      int r = row0 + wm*32 + mt*16 + l16;
      #pragma unroll
      for (int nt = 0; nt < 4; ++nt) {
        int c0 = col0 + wn*64 + nt*16 + quad*4;
        float4 b4 = *(const float4*)(Bv + c0);
        union { uint2 u; bf16 h[4]; } pk;
        pk.h[0] = __float2bfloat16((acc[mt][nt][0] + b4.x) * scale);
        pk.h[1] = __float2bfloat16((acc[mt][nt][1] + b4.y) * scale);
        pk.h[2] = __float2bfloat16((acc[mt][nt][2] + b4.z) * scale);
        pk.h[3] = __float2bfloat16((acc[mt][nt][3] + b4.w) * scale);
        *(uint2*)&C[(size_t)r*N + c0] = pk.u;
      }
    }
  } else {
    // V: D[m][c]; tokens quad*4+j contiguous -> 8B stores into VpT columns
    const int bb = row0 >> 11;
    const int sbase = (row0 & 2047) + wm*32;
    #pragma unroll
    for (int nt = 0; nt < 4; ++nt) {
      int c = col0 + wn*64 + nt*16 + l16;
      float bv = Bv[c];
      bf16* col = VpT + (size_t)((bb << 10) + c) * SEQ;
      #pragma unroll
      for (int mt = 0; mt < 2; ++mt) {
        int s = sbase + mt*16 + quad*4;
        union { uint2 u; bf16 h[4]; } pk;
        #pragma unroll
        for (int j = 0; j < 4; ++j) pk.h[j] = __float2bfloat16(acc[mt][nt][j] + bv);
        *(uint2*)(col + s) = pk.u;
      }
    }
  }
}

// ---------------------------------------------------------------------------
// Output projection, BK=64, 128x64 tile, swapped mfma -> float4 stores.
// Pipelined, counted vmcnt(6), XCD rectangular swizzle (round-10 verified).
// ---------------------------------------------------------------------------
__global__ __launch_bounds__(256) void gemm_out_dma(
    const bf16* __restrict__ A, const bf16* __restrict__ W,
    const float* __restrict__ Bv, float* __restrict__ C)
{
  __shared__ __align__(16) bf16 As[2][8*128*8];   // 2 x 16 KB
  __shared__ __align__(16) bf16 Ws[2][8*64*8];    // 2 x 8 KB
  const int K = D_MODEL, N = D_MODEL;
  const int tid  = threadIdx.x;
  const int lane = tid & 63, wave = tid >> 6;
  const int wm   = wave >> 1, wn = wave & 1;
  const int quad = lane >> 4, l16 = lane & 15;

  // XCD-aware rectangular remap (bijective over the 512-block grid)
  const int l    = blockIdx.x + (blockIdx.y << 4);  // hw linear, 0..511
  const int xcd  = l & 7, slot = l >> 3;            // slot 0..63
  const int bx   = slot & 15;                       // col tile 0..15
  const int by   = (xcd << 2) + (slot >> 4);        // row tile 0..31
  const int row0 = by * 128, col0 = bx * 64;

  const f32x4 zero = {0.f, 0.f, 0.f, 0.f};
  f32x4 acc[4][2];
  #pragma unroll
  for (int i = 0; i < 4; ++i)
    #pragma unroll
    for (int j = 0; j < 2; ++j) acc[i][j] = zero;

  // prologue: tile 0 (6 DMAs/thread)
  #pragma unroll
  for (int t = 0; t < 4; ++t) {
    int s = t*256 + tid;
    int g = s >> 7, r = s & 127;
    lds_dma16(A + (size_t)(row0 + r)*K + g*8, &As[0][s*8]);
  }
  #pragma unroll
  for (int t = 0; t < 2; ++t) {
    int s = t*256 + tid;
    int g = s >> 6, r = s & 63;
    lds_dma16(W + (size_t)(col0 + r)*K + g*8, &Ws[0][s*8]);
  }

  const int NT = K / 64;   // 16
  for (int kt = 0; kt < NT; ++kt) {
    const int cur = kt & 1;
    __builtin_amdgcn_s_barrier();            // (A)
    __builtin_amdgcn_sched_barrier(0);
    if (kt + 1 < NT) {
      const int k0n = (kt + 1) * 64;
      #pragma unroll
      for (int t = 0; t < 4; ++t) {
        int s = t*256 + tid;
        int g = s >> 7, r = s & 127;
        lds_dma16(A + (size_t)(row0 + r)*K + k0n + g*8, &As[cur^1][s*8]);
      }
      #pragma unroll
      for (int t = 0; t < 2; ++t) {
        int s = t*256 + tid;
        int g = s >> 6, r = s & 63;
        lds_dma16(W + (size_t)(col0 + r)*K + k0n + g*8, &Ws[cur^1][s*8]);
      }
      asm volatile("s_waitcnt vmcnt(6)" ::: "memory");
    } else {
      asm volatile("s_waitcnt vmcnt(0)" ::: "memory");
    }
    __builtin_amdgcn_sched_barrier(0);
    __builtin_amdgcn_s_barrier();            // (B)
    __builtin_amdgcn_sched_barrier(0);

    #pragma unroll
    for (int ks = 0; ks < 2; ++ks) {
      bf16x8 af[4], wf[2];
      #pragma unroll
      for (int mt = 0; mt < 4; ++mt)
        af[mt] = *(const bf16x8*)&As[cur][((ks*4 + quad)*128 + wm*64 + mt*16 + l16)*8];
      #pragma unroll
      for (int nt = 0; nt < 2; ++nt)
        wf[nt] = *(const bf16x8*)&Ws[cur][((ks*4 + quad)*64 + wn*32 + nt*16 + l16)*8];
      __builtin_amdgcn_s_setprio(1);
      #pragma unroll
      for (int mt = 0; mt < 4; ++mt)
        #pragma unroll
        for (int nt = 0; nt < 2; ++nt)
          acc[mt][nt] = __builtin_amdgcn_mfma_f32_16x16x32_bf16(wf[nt], af[mt], acc[mt][nt], 0, 0, 0);
      __builtin_amdgcn_s_setprio(0);
    }
    __builtin_amdgcn_sched_barrier(0);
  }

  #pragma unroll
  for (int mt = 0; mt < 4; ++mt) {
    int r = row0 + wm*64 + mt*16 + l16;
    #pragma unroll
    for (int nt = 0; nt < 2; ++nt) {
      int c0 = col0 + wn*32 + nt*16 + quad*4;
      float4 b4 = *(const float4*)(Bv + c0);
      float4 o;
      o.x = acc[mt][nt][0] + b4.x; o.y = acc[mt][nt][1] + b4.y;
      o.z = acc[mt][nt][2] + b4.z; o.w = acc[mt][nt][3] + b4.w;
      *(float4*)&C[(size_t)r*N + c0] = o;
    }
  }
}

// ---------------------------------------------------------------------------
// PATH B fallback (small ws): fused fp32->bf16 staging, BK=32, same
// swapped epilogues. 128x128 tile (unchanged).
// ---------------------------------------------------------------------------
__global__ __launch_bounds__(256) void gemm3_fused(
    const float* A0, const float* A1, const float* A2,
    const float* W0, const float* W1, const float* W2,
    const float* B0, const float* B1, const float* B2,
    bf16* C0, bf16* C1, bf16* VpT)
{
  __shared__ __align__(16) bf16 As[4*128*8];
  __shared__ __align__(16) bf16 Ws[4*128*8];
  const int z = blockIdx.z;
  const float* A = (z == 0) ? A0 : (z == 1) ? A1 : A2;
  const float* W = (z == 0) ? W0 : (z == 1) ? W1 : W2;
  const float* Bv = (z == 0) ? B0 : (z == 1) ? B1 : B2;
  const bool swapped = (z < 2);
  const int K = D_MODEL, N = D_MODEL;
  const int tid  = threadIdx.x;
  const int lane = tid & 63, wave = tid >> 6;
  const int wm   = wave >> 1, wn = wave & 1;
  const int quad = lane >> 4, l16 = lane & 15;
  const int row0 = blockIdx.y * 128, col0 = blockIdx.x * 128;

  const f32x4 zero = {0.f, 0.f, 0.f, 0.f};
  f32x4 acc[4][4];
  #pragma unroll
  for (int i = 0; i < 4; ++i)
    #pragma unroll
    for (int j = 0; j < 4; ++j) acc[i][j] = zero;

  for (int k0 = 0; k0 < K; k0 += 32) {
    __syncthreads();
    #pragma unroll
    for (int t = 0; t < 2; ++t) {
      int s = t*256 + tid;
      int g = s >> 7, r = s & 127;
      const float* Af = A + (size_t)(row0 + r)*K + k0 + g*8;
      *(uint4*)&As[s*8] = pack8_f32(((const float4*)Af)[0], ((const float4*)Af)[1]);
      const float* Wf = W + (size_t)(col0 + r)*K + k0 + g*8;
      *(uint4*)&Ws[s*8] = pack8_f32(((const float4*)Wf)[0], ((const float4*)Wf)[1]);
    }
    __syncthreads();
    bf16x8 af[4], wf[4];
    #pragma unroll
    for (int mt = 0; mt < 4; ++mt)
      af[mt] = *(const bf16x8*)&As[(quad*128 + wm*64 + mt*16 + l16)*8];
    #pragma unroll
    for (int nt = 0; nt < 4; ++nt)
      wf[nt] = *(const bf16x8*)&Ws[(quad*128 + wn*64 + nt*16 + l16)*8];
    if (swapped) {
      #pragma unroll
      for (int mt = 0; mt < 4; ++mt)
        #pragma unroll
        for (int nt = 0; nt < 4; ++nt)
          acc[mt][nt] = __builtin_amdgcn_mfma_f32_16x16x32_bf16(wf[nt], af[mt], acc[mt][nt], 0, 0, 0);
    } else {
      #pragma unroll
      for (int mt = 0; mt < 4; ++mt)
        #pragma unroll
        for (int nt = 0; nt < 4; ++nt)
          acc[mt][nt] = __builtin_amdgcn_mfma_f32_16x16x32_bf16(af[mt], wf[nt], acc[mt][nt], 0, 0, 0);
    }
  }

  if (swapped) {
    bf16* C = (z == 0) ? C0 : C1;
    const float scale = (z == 0) ? 0.125f*LOG2E : 1.0f;
    #pragma unroll
    for (int mt = 0; mt < 4; ++mt) {
      int r = row0 + wm*64 + mt*16 + l16;
      #pragma unroll
      for (int nt = 0; nt < 4; ++nt) {
        int c0 = col0 + wn*64 + nt*16 + quad*4;
        float4 b4 = *(const float4*)(Bv + c0);
        union { uint2 u; bf16 h[4]; } pk;
        pk.h[0] = __float2bfloat16((acc[mt][nt][0] + b4.x) * scale);
        pk.h[1] = __float2bfloat16((acc[mt][nt][1] + b4.y) * scale);
        pk.h[2] = __float2bfloat16((acc[mt][nt][2] + b4.z) * scale);
        pk.h[3] = __float2bfloat16((acc[mt][nt][3] + b4.w) * scale);
        *(uint2*)&C[(size_t)r*N + c0] = pk.u;
      }
    }
  } else {
    const int bb = row0 >> 11;
    const int sbase = (row0 & 2047) + wm*64;
    #pragma unroll
    for (int nt = 0; nt < 4; ++nt) {
      int c = col0 + wn*64 + nt*16 + l16;
      float bv = Bv[c];
      bf16* col = VpT + (size_t)((bb << 10) + c) * SEQ;
      #pragma unroll
      for (int mt = 0; mt < 4; ++mt) {
        int s = sbase + mt*16 + quad*4;
        union { uint2 u; bf16 h[4]; } pk;
        #pragma unroll
        for (int j = 0; j < 4; ++j) pk.h[j] = __float2bfloat16(acc[mt][nt][j] + bv);
        *(uint2*)(col + s) = pk.u;
      }
    }
  }
}

__global__ __launch_bounds__(256) void gemm_out_fused(
    const bf16* __restrict__ A, const float* __restrict__ W,
    const float* __restrict__ Bv, float* __restrict__ C)
{
  __shared__ __align__(16) bf16 As[4*128*8];
  __shared__ __align__(16) bf16 Ws[4*64*8];
  const int K = D_MODEL, N = D_MODEL;
  const int tid  = threadIdx.x;
  const int lane = tid & 63, wave = tid >> 6;
  const int wm   = wave >> 1, wn = wave & 1;
  const int quad = lane >> 4, l16 = lane & 15;
  const int row0 = blockIdx.y * 128, col0 = blockIdx.x * 64;

  const f32x4 zero = {0.f, 0.f, 0.f, 0.f};
  f32x4 acc[4][2];
  #pragma unroll
  for (int i = 0; i < 4; ++i)
    #pragma unroll
    for (int j = 0; j < 2; ++j) acc[i][j] = zero;

  for (int k0 = 0; k0 < K; k0 += 32) {
    __syncthreads();
    #pragma unroll
    for (int t = 0; t < 2; ++t) {
      int s = t*256 + tid;
      int g = s >> 7, r = s & 127;
      *(uint4*)&As[s*8] = *(const uint4*)(A + (size_t)(row0 + r)*K + k0 + g*8);
    }
    {
      int g = tid >> 6, r = tid & 63;
      const float* Wf = W + (size_t)(col0 + r)*K + k0 + g*8;
      *(uint4*)&Ws[tid*8] = pack8_f32(((const float4*)Wf)[0], ((const float4*)Wf)[1]);
    }
    __syncthreads();
    bf16x8 af[4], wf[2];
    #pragma unroll
    for (int mt = 0; mt < 4; ++mt)
      af[mt] = *(const bf16x8*)&As[(quad*128 + wm*64 + mt*16 + l16)*8];
    #pragma unroll
    for (int nt = 0; nt < 2; ++nt)
      wf[nt] = *(const bf16x8*)&Ws[(quad*64 + wn*32 + nt*16 + l16)*8];
    #pragma unroll
    for (int mt = 0; mt < 4; ++mt)
      #pragma unroll
      for (int nt = 0; nt < 2; ++nt)
        acc[mt][nt] = __builtin_amdgcn_mfma_f32_16x16x32_bf16(wf[nt], af[mt], acc[mt][nt], 0, 0, 0);
  }
  #pragma unroll
  for (int mt = 0; mt < 4; ++mt) {
    int r = row0 + wm*64 + mt*16 + l16;
    #pragma unroll
    for (int nt = 0; nt < 2; ++nt) {
      int c0 = col0 + wn*32 + nt*16 + quad*4;
      float4 b4 = *(const float4*)(Bv + c0);
      float4 o;
      o.x = acc[mt][nt][0] + b4.x; o.y = acc[mt][nt][1] + b4.y;
      o.z = acc[mt][nt][2] + b4.z; o.w = acc[mt][nt][3] + b4.w;
      *(float4*)&C[(size_t)r*N + c0] = o;
    }
  }
}

// ---------------------------------------------------------------------------
// Flash attention: 512 threads (8 waves x 16 q-rows), q-tile 128, K-tile 128.
// S^T = K Q^T, O^T = V^T P^T, log2-domain softmax. Pipelined Ks dbuf + raw
// s_barriers + XCD 2-heads-per-XCD swizzle (round-10 verified).
// ---------------------------------------------------------------------------
__global__ __launch_bounds__(512) void attn_fused(
    const bf16* __restrict__ Qp, const bf16* __restrict__ Kp,
    const bf16* __restrict__ VpT, bf16* __restrict__ Ao)
{
  __shared__ __align__(16) bf16 UN[128*128];      // 32 KB: Qs staging then Ps
  __shared__ __align__(16) bf16 Ks[2][8*128*8];   // 2 x 16 KB double-buffered
  __shared__ __align__(16) bf16 Vt[64*16*8];      // 16 KB  V^T swizzled

  const int tid  = threadIdx.x;
  const int lane = tid & 63, wave = tid >> 6;
  const int quad = lane >> 4, l16 = lane & 15;

  // XCD-aware remap: 2 heads per XCD
  const int l    = blockIdx.x + (blockIdx.y << 4);  // 0..255 per b-plane
  const int xcd  = l & 7, slot = l >> 3;            // slot 0..31
  const int qt   = slot & 15;
  const int h    = (xcd << 1) + (slot >> 4);
  const int b    = blockIdx.z;
  const int q0 = qt * 128;
  const bf16* Qb = Qp + ((size_t)b*SEQ + q0)*D_MODEL + h*DHEAD;
  const bf16* Kb = Kp + (size_t)b*SEQ*D_MODEL + h*DHEAD;
  const bf16* Vg = VpT + (size_t)((b << 10) + h*DHEAD) * SEQ;

  // V prefetch slots: thread handles chunks c0 = tid, c1 = 512+tid
  const int vn0 = tid >> 4,        vgk0 = tid & 15;
  const int vn1 = (512+tid) >> 4,  vgk1 = (512+tid) & 15;
  const int vsw0 = (vgk0 + vn0 + (vn0 >> 3)) & 15;
  const int vsw1 = (vgk1 + vn1 + (vn1 >> 3)) & 15;

  // ---- prologue: stage Q, K-tile 0, V-tile 0; one full drain ----
  #pragma unroll
  for (int t = 0; t < 2; ++t) {
    int s = t*512 + tid;
    int g = s >> 7, r = s & 127;
    lds_dma16(Qb + (size_t)r*D_MODEL + g*8, &UN[s*8]);
  }
  #pragma unroll
  for (int t = 0; t < 2; ++t) {
    int s = t*512 + tid;
    int g = s >> 7, kk = s & 127;
    lds_dma16(Kb + (size_t)kk*D_MODEL + g*8, &Ks[0][s*8]);
  }
  uint4 vreg0 = *(const uint4*)(Vg + (size_t)vn0*SEQ + vgk0*8);
  uint4 vreg1 = *(const uint4*)(Vg + (size_t)vn1*SEQ + vgk1*8);
  __syncthreads();   // full vmcnt+lgkm drain, once

  const int wq0 = wave * 16;
  const int q   = wq0 + l16;
  bf16x8 qa[2];
  #pragma unroll
  for (int ks = 0; ks < 2; ++ks)
    qa[ks] = *(const bf16x8*)&UN[((ks*4 + quad)*128 + q)*8];
  // qa must be fully loaded before any wave's Ps writes overwrite UN.
  asm volatile("s_waitcnt lgkmcnt(0)" ::: "memory");
  __builtin_amdgcn_sched_barrier(0);

  bf16* Ps = UN;
  const int swz = (l16 & 7) << 1;

  const f32x4 zero = {0.f, 0.f, 0.f, 0.f};
  f32x4 acc_o[4];
  #pragma unroll
  for (int dt = 0; dt < 4; ++dt) acc_o[dt] = zero;
  float m_s = -1e30f, l_s = 0.f;

  for (int kt = 0; kt < SEQ/128; ++kt) {
    const int cur = kt & 1;
    __builtin_amdgcn_s_barrier();            // bar1: all waves done PV(kt-1)
    __builtin_amdgcn_sched_barrier(0);

    // V^T tile: write prefetched regs (compiler vmcnt wait here drains the
    // loads issued LAST iteration -> hidden), then issue next tile's loads
    *(uint4*)&Vt[(vn0*16 + vsw0)*8] = vreg0;
    *(uint4*)&Vt[(vn1*16 + vsw1)*8] = vreg1;
    if (kt + 1 < SEQ/128) {
      // K tile kt+1 via DMA into the other buffer — stays in flight
      #pragma unroll
      for (int t = 0; t < 2; ++t) {
        int s = t*512 + tid;
        int g = s >> 7, kk = s & 127;
        lds_dma16(Kb + (size_t)((kt+1)*128 + kk)*D_MODEL + g*8, &Ks[cur^1][s*8]);
      }
      vreg0 = *(const uint4*)(Vg + (size_t)vn0*SEQ + (kt+1)*128 + vgk0*8);
      vreg1 = *(const uint4*)(Vg + (size_t)vn1*SEQ + (kt+1)*128 + vgk1*8);
    }
    asm volatile("s_waitcnt lgkmcnt(0)" ::: "memory");  // Vt writes visible
    __builtin_amdgcn_sched_barrier(0);
    __builtin_amdgcn_s_barrier();            // bar2: Vt + Ks[cur] ready
    __builtin_amdgcn_sched_barrier(0);

    // ---- S^T = K Q^T : D[key = kt2*16+quad*4+j][q = l16] ----
    f32x4 sc[8];
    #pragma unroll
    for (int kt2 = 0; kt2 < 8; ++kt2) sc[kt2] = zero;
    __builtin_amdgcn_s_setprio(1);
    #pragma unroll
    for (int ks = 0; ks < 2; ++ks) {
      bf16x8 kf[8];
      #pragma unroll
      for (int kt2 = 0; kt2 < 8; ++kt2)
        kf[kt2] = *(const bf16x8*)&Ks[cur][((ks*4 + quad)*128 + kt2*16 + l16)*8];
      #pragma unroll
      for (int kt2 = 0; kt2 < 8; ++kt2)
        sc[kt2] = __builtin_amdgcn_mfma_f32_16x16x32_bf16(kf[kt2], qa[ks], sc[kt2], 0, 0, 0);
    }
    __builtin_amdgcn_s_setprio(0);

    // ---- online softmax (log2 domain) ----
    float vmax = -1e30f;
    #pragma unroll
    for (int kt2 = 0; kt2 < 8; ++kt2) {
      f32x4 s4 = sc[kt2];
      vmax = fmaxf(vmax, fmaxf(fmaxf(s4[0], s4[1]), fmaxf(s4[2], s4[3])));
    }
    vmax = fmaxf(vmax, __shfl_xor(vmax, 16));
    vmax = fmaxf(vmax, __shfl_xor(vmax, 32));
    float mnew  = fmaxf(m_s, vmax);
    float alpha = __builtin_amdgcn_exp2f(m_s - mnew);
    float rs = 0.f;
    #pragma unroll
    for (int kt2 = 0; kt2 < 8; ++kt2) {
      float p0 = __builtin_amdgcn_exp2f(sc[kt2][0] - mnew);
      float p1 = __builtin_amdgcn_exp2f(sc[kt2][1] - mnew);
      float p2 = __builtin_amdgcn_exp2f(sc[kt2][2] - mnew);
      float p3 = __builtin_amdgcn_exp2f(sc[kt2][3] - mnew);
      rs += (p0 + p1) + (p2 + p3);
      union { uint2 u; bf16 hh[4]; } pk;
      pk.hh[0] = __float2bfloat16(p0); pk.hh[1] = __float2bfloat16(p1);
      pk.hh[2] = __float2bfloat16(p2); pk.hh[3] = __float2bfloat16(p3);
      int phys = (kt2*4 + quad) ^ swz;
      *(uint2*)&Ps[q*128 + phys*4] = pk.u;
    }
    rs += __shfl_xor(rs, 16);
    rs += __shfl_xor(rs, 32);
    l_s = l_s*alpha + rs;
    m_s = mnew;
    #pragma unroll
    for (int dt = 0; dt < 4; ++dt) acc_o[dt] = acc_o[dt] * alpha;
    // no barrier: Ps rows are wave-private; lgkmcnt orders write->read

    // ---- O^T += V^T P^T ----
    __builtin_amdgcn_s_setprio(1);
    #pragma unroll
    for (int ks2 = 0; ks2 < 4; ++ks2) {
      bf16x8 vf[4], pa;
      #pragma unroll
      for (int dt = 0; dt < 4; ++dt) {
        int n = dt*16 + l16;
        int sw = (ks2*4 + quad + n + (n >> 3)) & 15;
        vf[dt] = *(const bf16x8*)&Vt[(n*16 + sw)*8];
      }
      int phys = (ks2*8 + quad*2) ^ swz;
      pa = *(const bf16x8*)&Ps[q*128 + phys*4];
      #pragma unroll
      for (int dt = 0; dt < 4; ++dt)
        acc_o[dt] = __builtin_amdgcn_mfma_f32_16x16x32_bf16(vf[dt], pa, acc_o[dt], 0, 0, 0);
    }
    __builtin_amdgcn_s_setprio(0);
    // pin everything (PV ds_reads + their lgkm waits + MFMAs) before bar1
    __builtin_amdgcn_sched_barrier(0);
  }

  bf16* Ob = Ao + ((size_t)b*SEQ + q0)*D_MODEL + h*DHEAD;
  float inv = 1.f / l_s;
  #pragma unroll
  for (int dt = 0; dt < 4; ++dt) {
    union { uint2 u; bf16 hh[4]; } pk;
    #pragma unroll
    for (int j = 0; j < 4; ++j) pk.hh[j] = __float2bfloat16(acc_o[dt][j] * inv);
    *(uint2*)(Ob + (size_t)q*D_MODEL + dt*16 + quad*4) = pk.u;
  }
}

// ---------------------------------------------------------------------------
extern "C" void kernel_launch(void* const* d_in, const int* in_sizes, int n_in,
                              void* d_out, int out_size, void* d_ws, size_t ws_size,
                              hipStream_t stream) {
  const float* q   = (const float*)d_in[0];
  const float* k   = (const float*)d_in[1];
  const float* v   = (const float*)d_in[2];
  const float* w_q = (const float*)d_in[3];
  const float* b_q = (const float*)d_in[4];
  const float* w_k = (const float*)d_in[5];
  const float* b_k = (const float*)d_in[6];
  const float* w_v = (const float*)d_in[7];
  const float* b_v = (const float*)d_in[8];
  const float* w_o = (const float*)d_in[9];
  const float* b_o = (const float*)d_in[10];

  const size_t nbuf = (size_t)MROWS * D_MODEL;
  const size_t wbuf = (size_t)D_MODEL * D_MODEL;
  bf16* Kp  = (bf16*)d_out;                       // d_out (fp32,16.8MB) scratch
  bf16* VpT = Kp + nbuf;

  // PATH A: 4 bf16 weight copies + Qp (activations read fp32 inline)
  const size_t needA = 256 + (4*wbuf + nbuf) * 2;   // ~16.8 MB
  if (ws_size >= needA) {
    bf16* wqc = (bf16*)((char*)d_ws + 256);
    bf16* wkc = wqc + wbuf;
    bf16* wvc = wkc + wbuf;
    bf16* woc = wvc + wbuf;
    bf16* Qp  = woc + wbuf;
    bf16* Ao  = Qp;                   // alias: block-local slices only

    convert4<<<dim3(128,4), 256, 0, stream>>>(w_q, w_k, w_v, w_o,
                                              wqc, wkc, wvc, woc);
    gemm3_dma<<<dim3(8,32,3), 512, 0, stream>>>(q, k, v, wqc, wkc, wvc,
                                                b_q, b_k, b_v, Qp, Kp, VpT);
    attn_fused<<<dim3(16,16,2), 512, 0, stream>>>(Qp, Kp, VpT, Ao);
    gemm_out_dma<<<dim3(16,32), 256, 0, stream>>>(Ao, woc, b_o, (float*)d_out);
  } else {
    bf16* Qp = (bf16*)((char*)d_ws + 256);
    bf16* Ao = Qp;
    gemm3_fused<<<dim3(8,32,3), 256, 0, stream>>>(q, k, v, w_q, w_k, w_v,
                                                  b_q, b_k, b_v, Qp, Kp, VpT);
    attn_fused<<<dim3(16,16,2), 512, 0, stream>>>(Qp, Kp, VpT, Ao);
    gemm_out_fused<<<dim3(16,32), 256, 0, stream>>>(Ao, w_o, b_o, (float*)d_out);
  }
}

// Round 12
// 261.804 us; speedup vs baseline: 1.0677x; 1.0677x over previous
//
#include <hip/hip_runtime.h>
#include <hip/hip_bf16.h>

typedef __hip_bfloat16 bf16;
typedef short bf16x8 __attribute__((ext_vector_type(8)));   // 8 bf16 = 4 VGPRs
typedef float f32x4 __attribute__((ext_vector_type(4)));    // C/D frag

#define D_MODEL 1024
#define SEQ     2048
#define NHEAD   16
#define DHEAD   64
#define BATCH   2
#define MROWS   (BATCH*SEQ)   // 4096
#define LOG2E   1.4426950408889634f

// async global->LDS, 16B per lane (m97 lever). Dest = wave-uniform base +
// lane*16 (m104/m108) — all call sites satisfy this.
__device__ __forceinline__ void lds_dma16(const bf16* g, bf16* l) {
  __builtin_amdgcn_global_load_lds(
      (const __attribute__((address_space(1))) void*)g,
      (__attribute__((address_space(3))) void*)l, 16, 0, 0);
}

__device__ __forceinline__ uint4 pack8_f32(const float4 x0, const float4 x1) {
  union { uint4 q; bf16 h[8]; } pk;
  pk.h[0]=__float2bfloat16(x0.x); pk.h[1]=__float2bfloat16(x0.y);
  pk.h[2]=__float2bfloat16(x0.z); pk.h[3]=__float2bfloat16(x0.w);
  pk.h[4]=__float2bfloat16(x1.x); pk.h[5]=__float2bfloat16(x1.y);
  pk.h[6]=__float2bfloat16(x1.z); pk.h[7]=__float2bfloat16(x1.w);
  return pk.q;
}

// ---------------------------------------------------------------------------
// Convert 7 fp32 buffers -> bf16. grid (512,7). (Inline activation
// conversion rejected twice: r7 traffic blow-up, r11 critical-path cost.)
// ---------------------------------------------------------------------------
__global__ __launch_bounds__(256) void convert7(
    const float* s0, const float* s1, const float* s2, const float* s3,
    const float* s4, const float* s5, const float* s6,
    bf16* d0, bf16* d1, bf16* d2, bf16* d3, bf16* d4, bf16* d5, bf16* d6)
{
  const float* S[7] = {s0,s1,s2,s3,s4,s5,s6};
  bf16*        D[7] = {d0,d1,d2,d3,d4,d5,d6};
  const int z = blockIdx.y;
  const int n8 = (z < 3) ? (MROWS*D_MODEL/8) : (D_MODEL*D_MODEL/8);
  for (int i = blockIdx.x*256 + threadIdx.x; i < n8; i += 512*256) {
    float4 a = ((const float4*)S[z])[2*i];
    float4 b = ((const float4*)S[z])[2*i+1];
    ((uint4*)D[z])[i] = pack8_f32(a, b);
  }
}

// ---------------------------------------------------------------------------
// QKV GEMM. 128x128 tile, 512 threads / 8 waves (4wm x 2wn), per-wave 32x64.
// XCD rectangular swizzle (round-9: FETCH 101->37MB). 48 KB LDS, A-side
// reg-staged from BF16 (round-10 verified, 69.0 µs). Structure floor —
// ledger: counted-vmcnt null, 2x TLP null, 256^2 RA-blocked, fp32 fusion
// regressed twice (traffic r7 / latency r11).
// ---------------------------------------------------------------------------
__global__ __launch_bounds__(512) void gemm3_dma(
    const bf16* A0, const bf16* A1, const bf16* A2,
    const bf16* W0, const bf16* W1, const bf16* W2,
    const float* B0, const float* B1, const float* B2,
    bf16* C0, bf16* C1, bf16* VpT)
{
  __shared__ __align__(16) bf16 As[8*128*8];      // 16 KB single-buffer
  __shared__ __align__(16) bf16 Ws[2][8*128*8];   // 2 x 16 KB dbuf
  const int z = blockIdx.z;
  const bf16* A = (z == 0) ? A0 : (z == 1) ? A1 : A2;
  const bf16* W = (z == 0) ? W0 : (z == 1) ? W1 : W2;
  const float* Bv = (z == 0) ? B0 : (z == 1) ? B1 : B2;
  const bool swapped = (z < 2);
  const int K = D_MODEL, N = D_MODEL;
  const int tid  = threadIdx.x;
  const int lane = tid & 63, wave = tid >> 6;     // wave 0..7
  const int wm   = wave >> 1, wn = wave & 1;      // 4 x 2
  const int quad = lane >> 4, l16 = lane & 15;

  // XCD-aware rectangular remap (bijective within each z-plane of 256):
  // each XCD owns a 4x8 (y,x) rectangle -> 1MB A + 2MB W per XCD < 4MB L2.
  const int l    = blockIdx.x + (blockIdx.y << 3);  // hw linear, 0..255
  const int xcd  = l & 7, slot = l >> 3;
  const int bx   = slot & 7;
  const int by   = (xcd << 2) + (slot >> 3);
  const int row0 = by * 128, col0 = bx * 128;

  // A reg-staging slots: thread handles chunks (g_, r_) and (g_+4, r_)
  const int r_ = tid & 127, g_ = tid >> 7;        // g_ in 0..3
  const bf16* Arow = A + (size_t)(row0 + r_)*K;

  const f32x4 zero = {0.f, 0.f, 0.f, 0.f};
  f32x4 acc[2][4];
  #pragma unroll
  for (int i = 0; i < 2; ++i)
    #pragma unroll
    for (int j = 0; j < 4; ++j) acc[i][j] = zero;

  // prologue: rA(0) FIRST (older in vmcnt queue), then W(0) DMA
  uint4 rA0 = *(const uint4*)(Arow + g_*8);
  uint4 rA1 = *(const uint4*)(Arow + (4+g_)*8);
  #pragma unroll
  for (int t = 0; t < 2; ++t) {
    int s = t*512 + tid;
    int g = s >> 7, r = s & 127;
    lds_dma16(W + (size_t)(col0 + r)*K + g*8, &Ws[0][s*8]);
  }

  const int NT = K / 64;   // 16
  for (int kt = 0; kt < NT; ++kt) {
    const int cur = kt & 1;
    __builtin_amdgcn_s_barrier();            // (A) all done compute(kt-1)
    __builtin_amdgcn_sched_barrier(0);
    // ds_write A(kt): compiler waits vmcnt(2) (rA oldest; W(kt) in flight)
    *(uint4*)&As[(g_*128 + r_)*8]     = rA0;
    *(uint4*)&As[((4+g_)*128 + r_)*8] = rA1;
    if (kt + 1 < NT) {
      const int k0n = (kt + 1) * 64;
      rA0 = *(const uint4*)(Arow + k0n + g_*8);
      rA1 = *(const uint4*)(Arow + k0n + (4+g_)*8);
      #pragma unroll
      for (int t = 0; t < 2; ++t) {
        int s = t*512 + tid;
        int g = s >> 7, r = s & 127;
        lds_dma16(W + (size_t)(col0 + r)*K + k0n + g*8, &Ws[cur^1][s*8]);
      }
      // outstanding: [W(kt)x2, rA(kt+1)x2, W(kt+1)x2] -> drain W(kt) only
      asm volatile("s_waitcnt vmcnt(4)" ::: "memory");
    } else {
      asm volatile("s_waitcnt vmcnt(0)" ::: "memory");  // final drain
    }
    __builtin_amdgcn_sched_barrier(0);
    asm volatile("s_waitcnt lgkmcnt(0)" ::: "memory");  // A ds_writes done
    __builtin_amdgcn_sched_barrier(0);
    __builtin_amdgcn_s_barrier();            // (B) As + Ws[cur] ready
    __builtin_amdgcn_sched_barrier(0);

    #pragma unroll
    for (int ks = 0; ks < 2; ++ks) {
      bf16x8 af[2], wf[4];
      #pragma unroll
      for (int mt = 0; mt < 2; ++mt)
        af[mt] = *(const bf16x8*)&As[((ks*4 + quad)*128 + wm*32 + mt*16 + l16)*8];
      #pragma unroll
      for (int nt = 0; nt < 4; ++nt)
        wf[nt] = *(const bf16x8*)&Ws[cur][((ks*4 + quad)*128 + wn*64 + nt*16 + l16)*8];
      __builtin_amdgcn_s_setprio(1);
      if (swapped) {
        #pragma unroll
        for (int mt = 0; mt < 2; ++mt)
          #pragma unroll
          for (int nt = 0; nt < 4; ++nt)
            acc[mt][nt] = __builtin_amdgcn_mfma_f32_16x16x32_bf16(wf[nt], af[mt], acc[mt][nt], 0, 0, 0);
      } else {
        #pragma unroll
        for (int mt = 0; mt < 2; ++mt)
          #pragma unroll
          for (int nt = 0; nt < 4; ++nt)
            acc[mt][nt] = __builtin_amdgcn_mfma_f32_16x16x32_bf16(af[mt], wf[nt], acc[mt][nt], 0, 0, 0);
      }
      __builtin_amdgcn_s_setprio(0);
    }
    // pin compute (ds_reads + MFMAs) before next iteration's bar(A)
    __builtin_amdgcn_sched_barrier(0);
  }

  if (swapped) {
    bf16* C = (z == 0) ? C0 : C1;
    const float scale = (z == 0) ? 0.125f*LOG2E : 1.0f;
    // D[c][m]: lane holds cols c0..c0+3 of row r -> 8B packed stores
    #pragma unroll
    for (int mt = 0; mt < 2; ++mt) {
      int r = row0 + wm*32 + mt*16 + l16;
      #pragma unroll
      for (int nt = 0; nt < 4; ++nt) {
        int c0 = col0 + wn*64 + nt*16 + quad*4;
        float4 b4 = *(const float4*)(Bv + c0);
        union { uint2 u; bf16 h[4]; } pk;
        pk.h[0] = __float2bfloat16((acc[mt][nt][0] + b4.x) * scale);
        pk.h[1] = __float2bfloat16((acc[mt][nt][1] + b4.y) * scale);
        pk.h[2] = __float2bfloat16((acc[mt][nt][2] + b4.z) * scale);
        pk.h[3] = __float2bfloat16((acc[mt][nt][3] + b4.w) * scale);
        *(uint2*)&C[(size_t)r*N + c0] = pk.u;
      }
    }
  } else {
    // V: D[m][c]; tokens quad*4+j contiguous -> 8B stores into VpT columns
    const int bb = row0 >> 11;
    const int sbase = (row0 & 2047) + wm*32;
    #pragma unroll
    for (int nt = 0; nt < 4; ++nt) {
      int c = col0 + wn*64 + nt*16 + l16;
      float bv = Bv[c];
      bf16* col = VpT + (size_t)((bb << 10) + c) * SEQ;
      #pragma unroll
      for (int mt = 0; mt < 2; ++mt) {
        int s = sbase + mt*16 + quad*4;
        union { uint2 u; bf16 h[4]; } pk;
        #pragma unroll
        for (int j = 0; j < 4; ++j) pk.h[j] = __float2bfloat16(acc[mt][nt][j] + bv);
        *(uint2*)(col + s) = pk.u;
      }
    }
  }
}

// ---------------------------------------------------------------------------
// Output projection, BK=64, 128x64 tile, swapped mfma -> float4 stores.
// Pipelined, counted vmcnt(6), XCD rectangular swizzle (round-10 verified).
// ---------------------------------------------------------------------------
__global__ __launch_bounds__(256) void gemm_out_dma(
    const bf16* __restrict__ A, const bf16* __restrict__ W,
    const float* __restrict__ Bv, float* __restrict__ C)
{
  __shared__ __align__(16) bf16 As[2][8*128*8];   // 2 x 16 KB
  __shared__ __align__(16) bf16 Ws[2][8*64*8];    // 2 x 8 KB
  const int K = D_MODEL, N = D_MODEL;
  const int tid  = threadIdx.x;
  const int lane = tid & 63, wave = tid >> 6;
  const int wm   = wave >> 1, wn = wave & 1;
  const int quad = lane >> 4, l16 = lane & 15;

  // XCD-aware rectangular remap (bijective over the 512-block grid)
  const int l    = blockIdx.x + (blockIdx.y << 4);  // hw linear, 0..511
  const int xcd  = l & 7, slot = l >> 3;            // slot 0..63
  const int bx   = slot & 15;                       // col tile 0..15
  const int by   = (xcd << 2) + (slot >> 4);        // row tile 0..31
  const int row0 = by * 128, col0 = bx * 64;

  const f32x4 zero = {0.f, 0.f, 0.f, 0.f};
  f32x4 acc[4][2];
  #pragma unroll
  for (int i = 0; i < 4; ++i)
    #pragma unroll
    for (int j = 0; j < 2; ++j) acc[i][j] = zero;

  // prologue: tile 0 (6 DMAs/thread)
  #pragma unroll
  for (int t = 0; t < 4; ++t) {
    int s = t*256 + tid;
    int g = s >> 7, r = s & 127;
    lds_dma16(A + (size_t)(row0 + r)*K + g*8, &As[0][s*8]);
  }
  #pragma unroll
  for (int t = 0; t < 2; ++t) {
    int s = t*256 + tid;
    int g = s >> 6, r = s & 63;
    lds_dma16(W + (size_t)(col0 + r)*K + g*8, &Ws[0][s*8]);
  }

  const int NT = K / 64;   // 16
  for (int kt = 0; kt < NT; ++kt) {
    const int cur = kt & 1;
    __builtin_amdgcn_s_barrier();            // (A)
    __builtin_amdgcn_sched_barrier(0);
    if (kt + 1 < NT) {
      const int k0n = (kt + 1) * 64;
      #pragma unroll
      for (int t = 0; t < 4; ++t) {
        int s = t*256 + tid;
        int g = s >> 7, r = s & 127;
        lds_dma16(A + (size_t)(row0 + r)*K + k0n + g*8, &As[cur^1][s*8]);
      }
      #pragma unroll
      for (int t = 0; t < 2; ++t) {
        int s = t*256 + tid;
        int g = s >> 6, r = s & 63;
        lds_dma16(W + (size_t)(col0 + r)*K + k0n + g*8, &Ws[cur^1][s*8]);
      }
      asm volatile("s_waitcnt vmcnt(6)" ::: "memory");
    } else {
      asm volatile("s_waitcnt vmcnt(0)" ::: "memory");
    }
    __builtin_amdgcn_sched_barrier(0);
    __builtin_amdgcn_s_barrier();            // (B)
    __builtin_amdgcn_sched_barrier(0);

    #pragma unroll
    for (int ks = 0; ks < 2; ++ks) {
      bf16x8 af[4], wf[2];
      #pragma unroll
      for (int mt = 0; mt < 4; ++mt)
        af[mt] = *(const bf16x8*)&As[cur][((ks*4 + quad)*128 + wm*64 + mt*16 + l16)*8];
      #pragma unroll
      for (int nt = 0; nt < 2; ++nt)
        wf[nt] = *(const bf16x8*)&Ws[cur][((ks*4 + quad)*64 + wn*32 + nt*16 + l16)*8];
      __builtin_amdgcn_s_setprio(1);
      #pragma unroll
      for (int mt = 0; mt < 4; ++mt)
        #pragma unroll
        for (int nt = 0; nt < 2; ++nt)
          acc[mt][nt] = __builtin_amdgcn_mfma_f32_16x16x32_bf16(wf[nt], af[mt], acc[mt][nt], 0, 0, 0);
      __builtin_amdgcn_s_setprio(0);
    }
    __builtin_amdgcn_sched_barrier(0);
  }

  #pragma unroll
  for (int mt = 0; mt < 4; ++mt) {
    int r = row0 + wm*64 + mt*16 + l16;
    #pragma unroll
    for (int nt = 0; nt < 2; ++nt) {
      int c0 = col0 + wn*32 + nt*16 + quad*4;
      float4 b4 = *(const float4*)(Bv + c0);
      float4 o;
      o.x = acc[mt][nt][0] + b4.x; o.y = acc[mt][nt][1] + b4.y;
      o.z = acc[mt][nt][2] + b4.z; o.w = acc[mt][nt][3] + b4.w;
      *(float4*)&C[(size_t)r*N + c0] = o;
    }
  }
}

// ---------------------------------------------------------------------------
// PATH B fallback (small ws): fused fp32->bf16 staging, BK=32, same
// swapped epilogues. 128x128 tile (unchanged).
// ---------------------------------------------------------------------------
__global__ __launch_bounds__(256) void gemm3_fused(
    const float* A0, const float* A1, const float* A2,
    const float* W0, const float* W1, const float* W2,
    const float* B0, const float* B1, const float* B2,
    bf16* C0, bf16* C1, bf16* VpT)
{
  __shared__ __align__(16) bf16 As[4*128*8];
  __shared__ __align__(16) bf16 Ws[4*128*8];
  const int z = blockIdx.z;
  const float* A = (z == 0) ? A0 : (z == 1) ? A1 : A2;
  const float* W = (z == 0) ? W0 : (z == 1) ? W1 : W2;
  const float* Bv = (z == 0) ? B0 : (z == 1) ? B1 : B2;
  const bool swapped = (z < 2);
  const int K = D_MODEL, N = D_MODEL;
  const int tid  = threadIdx.x;
  const int lane = tid & 63, wave = tid >> 6;
  const int wm   = wave >> 1, wn = wave & 1;
  const int quad = lane >> 4, l16 = lane & 15;
  const int row0 = blockIdx.y * 128, col0 = blockIdx.x * 128;

  const f32x4 zero = {0.f, 0.f, 0.f, 0.f};
  f32x4 acc[4][4];
  #pragma unroll
  for (int i = 0; i < 4; ++i)
    #pragma unroll
    for (int j = 0; j < 4; ++j) acc[i][j] = zero;

  for (int k0 = 0; k0 < K; k0 += 32) {
    __syncthreads();
    #pragma unroll
    for (int t = 0; t < 2; ++t) {
      int s = t*256 + tid;
      int g = s >> 7, r = s & 127;
      const float* Af = A + (size_t)(row0 + r)*K + k0 + g*8;
      *(uint4*)&As[s*8] = pack8_f32(((const float4*)Af)[0], ((const float4*)Af)[1]);
      const float* Wf = W + (size_t)(col0 + r)*K + k0 + g*8;
      *(uint4*)&Ws[s*8] = pack8_f32(((const float4*)Wf)[0], ((const float4*)Wf)[1]);
    }
    __syncthreads();
    bf16x8 af[4], wf[4];
    #pragma unroll
    for (int mt = 0; mt < 4; ++mt)
      af[mt] = *(const bf16x8*)&As[(quad*128 + wm*64 + mt*16 + l16)*8];
    #pragma unroll
    for (int nt = 0; nt < 4; ++nt)
      wf[nt] = *(const bf16x8*)&Ws[(quad*128 + wn*64 + nt*16 + l16)*8];
    if (swapped) {
      #pragma unroll
      for (int mt = 0; mt < 4; ++mt)
        #pragma unroll
        for (int nt = 0; nt < 4; ++nt)
          acc[mt][nt] = __builtin_amdgcn_mfma_f32_16x16x32_bf16(wf[nt], af[mt], acc[mt][nt], 0, 0, 0);
    } else {
      #pragma unroll
      for (int mt = 0; mt < 4; ++mt)
        #pragma unroll
        for (int nt = 0; nt < 4; ++nt)
          acc[mt][nt] = __builtin_amdgcn_mfma_f32_16x16x32_bf16(af[mt], wf[nt], acc[mt][nt], 0, 0, 0);
    }
  }

  if (swapped) {
    bf16* C = (z == 0) ? C0 : C1;
    const float scale = (z == 0) ? 0.125f*LOG2E : 1.0f;
    #pragma unroll
    for (int mt = 0; mt < 4; ++mt) {
      int r = row0 + wm*64 + mt*16 + l16;
      #pragma unroll
      for (int nt = 0; nt < 4; ++nt) {
        int c0 = col0 + wn*64 + nt*16 + quad*4;
        float4 b4 = *(const float4*)(Bv + c0);
        union { uint2 u; bf16 h[4]; } pk;
        pk.h[0] = __float2bfloat16((acc[mt][nt][0] + b4.x) * scale);
        pk.h[1] = __float2bfloat16((acc[mt][nt][1] + b4.y) * scale);
        pk.h[2] = __float2bfloat16((acc[mt][nt][2] + b4.z) * scale);
        pk.h[3] = __float2bfloat16((acc[mt][nt][3] + b4.w) * scale);
        *(uint2*)&C[(size_t)r*N + c0] = pk.u;
      }
    }
  } else {
    const int bb = row0 >> 11;
    const int sbase = (row0 & 2047) + wm*64;
    #pragma unroll
    for (int nt = 0; nt < 4; ++nt) {
      int c = col0 + wn*64 + nt*16 + l16;
      float bv = Bv[c];
      bf16* col = VpT + (size_t)((bb << 10) + c) * SEQ;
      #pragma unroll
      for (int mt = 0; mt < 4; ++mt) {
        int s = sbase + mt*16 + quad*4;
        union { uint2 u; bf16 h[4]; } pk;
        #pragma unroll
        for (int j = 0; j < 4; ++j) pk.h[j] = __float2bfloat16(acc[mt][nt][j] + bv);
        *(uint2*)(col + s) = pk.u;
      }
    }
  }
}

__global__ __launch_bounds__(256) void gemm_out_fused(
    const bf16* __restrict__ A, const float* __restrict__ W,
    const float* __restrict__ Bv, float* __restrict__ C)
{
  __shared__ __align__(16) bf16 As[4*128*8];
  __shared__ __align__(16) bf16 Ws[4*64*8];
  const int K = D_MODEL, N = D_MODEL;
  const int tid  = threadIdx.x;
  const int lane = tid & 63, wave = tid >> 6;
  const int wm   = wave >> 1, wn = wave & 1;
  const int quad = lane >> 4, l16 = lane & 15;
  const int row0 = blockIdx.y * 128, col0 = blockIdx.x * 64;

  const f32x4 zero = {0.f, 0.f, 0.f, 0.f};
  f32x4 acc[4][2];
  #pragma unroll
  for (int i = 0; i < 4; ++i)
    #pragma unroll
    for (int j = 0; j < 2; ++j) acc[i][j] = zero;

  for (int k0 = 0; k0 < K; k0 += 32) {
    __syncthreads();
    #pragma unroll
    for (int t = 0; t < 2; ++t) {
      int s = t*256 + tid;
      int g = s >> 7, r = s & 127;
      *(uint4*)&As[s*8] = *(const uint4*)(A + (size_t)(row0 + r)*K + k0 + g*8);
    }
    {
      int g = tid >> 6, r = tid & 63;
      const float* Wf = W + (size_t)(col0 + r)*K + k0 + g*8;
      *(uint4*)&Ws[tid*8] = pack8_f32(((const float4*)Wf)[0], ((const float4*)Wf)[1]);
    }
    __syncthreads();
    bf16x8 af[4], wf[2];
    #pragma unroll
    for (int mt = 0; mt < 4; ++mt)
      af[mt] = *(const bf16x8*)&As[(quad*128 + wm*64 + mt*16 + l16)*8];
    #pragma unroll
    for (int nt = 0; nt < 2; ++nt)
      wf[nt] = *(const bf16x8*)&Ws[(quad*64 + wn*32 + nt*16 + l16)*8];
    #pragma unroll
    for (int mt = 0; mt < 4; ++mt)
      #pragma unroll
      for (int nt = 0; nt < 2; ++nt)
        acc[mt][nt] = __builtin_amdgcn_mfma_f32_16x16x32_bf16(wf[nt], af[mt], acc[mt][nt], 0, 0, 0);
  }
  #pragma unroll
  for (int mt = 0; mt < 4; ++mt) {
    int r = row0 + wm*64 + mt*16 + l16;
    #pragma unroll
    for (int nt = 0; nt < 2; ++nt) {
      int c0 = col0 + wn*32 + nt*16 + quad*4;
      float4 b4 = *(const float4*)(Bv + c0);
      float4 o;
      o.x = acc[mt][nt][0] + b4.x; o.y = acc[mt][nt][1] + b4.y;
      o.z = acc[mt][nt][2] + b4.z; o.w = acc[mt][nt][3] + b4.w;
      *(float4*)&C[(size_t)r*N + c0] = o;
    }
  }
}

// ---------------------------------------------------------------------------
// Flash attention: 512 threads (8 waves x 16 q-rows), q-tile 128, K-tile 128.
// S^T = K Q^T, O^T = V^T P^T, log2-domain softmax. Pipelined Ks dbuf + raw
// s_barriers + XCD 2-heads-per-XCD swizzle (round-10 verified).
// ---------------------------------------------------------------------------
__global__ __launch_bounds__(512) void attn_fused(
    const bf16* __restrict__ Qp, const bf16* __restrict__ Kp,
    const bf16* __restrict__ VpT, bf16* __restrict__ Ao)
{
  __shared__ __align__(16) bf16 UN[128*128];      // 32 KB: Qs staging then Ps
  __shared__ __align__(16) bf16 Ks[2][8*128*8];   // 2 x 16 KB double-buffered
  __shared__ __align__(16) bf16 Vt[64*16*8];      // 16 KB  V^T swizzled

  const int tid  = threadIdx.x;
  const int lane = tid & 63, wave = tid >> 6;
  const int quad = lane >> 4, l16 = lane & 15;

  // XCD-aware remap: 2 heads per XCD
  const int l    = blockIdx.x + (blockIdx.y << 4);  // 0..255 per b-plane
  const int xcd  = l & 7, slot = l >> 3;            // slot 0..31
  const int qt   = slot & 15;
  const int h    = (xcd << 1) + (slot >> 4);
  const int b    = blockIdx.z;
  const int q0 = qt * 128;
  const bf16* Qb = Qp + ((size_t)b*SEQ + q0)*D_MODEL + h*DHEAD;
  const bf16* Kb = Kp + (size_t)b*SEQ*D_MODEL + h*DHEAD;
  const bf16* Vg = VpT + (size_t)((b << 10) + h*DHEAD) * SEQ;

  // V prefetch slots: thread handles chunks c0 = tid, c1 = 512+tid
  const int vn0 = tid >> 4,        vgk0 = tid & 15;
  const int vn1 = (512+tid) >> 4,  vgk1 = (512+tid) & 15;
  const int vsw0 = (vgk0 + vn0 + (vn0 >> 3)) & 15;
  const int vsw1 = (vgk1 + vn1 + (vn1 >> 3)) & 15;

  // ---- prologue: stage Q, K-tile 0, V-tile 0; one full drain ----
  #pragma unroll
  for (int t = 0; t < 2; ++t) {
    int s = t*512 + tid;
    int g = s >> 7, r = s & 127;
    lds_dma16(Qb + (size_t)r*D_MODEL + g*8, &UN[s*8]);
  }
  #pragma unroll
  for (int t = 0; t < 2; ++t) {
    int s = t*512 + tid;
    int g = s >> 7, kk = s & 127;
    lds_dma16(Kb + (size_t)kk*D_MODEL + g*8, &Ks[0][s*8]);
  }
  uint4 vreg0 = *(const uint4*)(Vg + (size_t)vn0*SEQ + vgk0*8);
  uint4 vreg1 = *(const uint4*)(Vg + (size_t)vn1*SEQ + vgk1*8);
  __syncthreads();   // full vmcnt+lgkm drain, once

  const int wq0 = wave * 16;
  const int q   = wq0 + l16;
  bf16x8 qa[2];
  #pragma unroll
  for (int ks = 0; ks < 2; ++ks)
    qa[ks] = *(const bf16x8*)&UN[((ks*4 + quad)*128 + q)*8];
  // qa must be fully loaded before any wave's Ps writes overwrite UN.
  asm volatile("s_waitcnt lgkmcnt(0)" ::: "memory");
  __builtin_amdgcn_sched_barrier(0);

  bf16* Ps = UN;
  const int swz = (l16 & 7) << 1;

  const f32x4 zero = {0.f, 0.f, 0.f, 0.f};
  f32x4 acc_o[4];
  #pragma unroll
  for (int dt = 0; dt < 4; ++dt) acc_o[dt] = zero;
  float m_s = -1e30f, l_s = 0.f;

  for (int kt = 0; kt < SEQ/128; ++kt) {
    const int cur = kt & 1;
    __builtin_amdgcn_s_barrier();            // bar1: all waves done PV(kt-1)
    __builtin_amdgcn_sched_barrier(0);

    // V^T tile: write prefetched regs (compiler vmcnt wait here drains the
    // loads issued LAST iteration -> hidden), then issue next tile's loads
    *(uint4*)&Vt[(vn0*16 + vsw0)*8] = vreg0;
    *(uint4*)&Vt[(vn1*16 + vsw1)*8] = vreg1;
    if (kt + 1 < SEQ/128) {
      // K tile kt+1 via DMA into the other buffer — stays in flight
      #pragma unroll
      for (int t = 0; t < 2; ++t) {
        int s = t*512 + tid;
        int g = s >> 7, kk = s & 127;
        lds_dma16(Kb + (size_t)((kt+1)*128 + kk)*D_MODEL + g*8, &Ks[cur^1][s*8]);
      }
      vreg0 = *(const uint4*)(Vg + (size_t)vn0*SEQ + (kt+1)*128 + vgk0*8);
      vreg1 = *(const uint4*)(Vg + (size_t)vn1*SEQ + (kt+1)*128 + vgk1*8);
    }
    asm volatile("s_waitcnt lgkmcnt(0)" ::: "memory");  // Vt writes visible
    __builtin_amdgcn_sched_barrier(0);
    __builtin_amdgcn_s_barrier();            // bar2: Vt + Ks[cur] ready
    __builtin_amdgcn_sched_barrier(0);

    // ---- S^T = K Q^T : D[key = kt2*16+quad*4+j][q = l16] ----
    f32x4 sc[8];
    #pragma unroll
    for (int kt2 = 0; kt2 < 8; ++kt2) sc[kt2] = zero;
    __builtin_amdgcn_s_setprio(1);
    #pragma unroll
    for (int ks = 0; ks < 2; ++ks) {
      bf16x8 kf[8];
      #pragma unroll
      for (int kt2 = 0; kt2 < 8; ++kt2)
        kf[kt2] = *(const bf16x8*)&Ks[cur][((ks*4 + quad)*128 + kt2*16 + l16)*8];
      #pragma unroll
      for (int kt2 = 0; kt2 < 8; ++kt2)
        sc[kt2] = __builtin_amdgcn_mfma_f32_16x16x32_bf16(kf[kt2], qa[ks], sc[kt2], 0, 0, 0);
    }
    __builtin_amdgcn_s_setprio(0);

    // ---- online softmax (log2 domain) ----
    float vmax = -1e30f;
    #pragma unroll
    for (int kt2 = 0; kt2 < 8; ++kt2) {
      f32x4 s4 = sc[kt2];
      vmax = fmaxf(vmax, fmaxf(fmaxf(s4[0], s4[1]), fmaxf(s4[2], s4[3])));
    }
    vmax = fmaxf(vmax, __shfl_xor(vmax, 16));
    vmax = fmaxf(vmax, __shfl_xor(vmax, 32));
    float mnew  = fmaxf(m_s, vmax);
    float alpha = __builtin_amdgcn_exp2f(m_s - mnew);
    float rs = 0.f;
    #pragma unroll
    for (int kt2 = 0; kt2 < 8; ++kt2) {
      float p0 = __builtin_amdgcn_exp2f(sc[kt2][0] - mnew);
      float p1 = __builtin_amdgcn_exp2f(sc[kt2][1] - mnew);
      float p2 = __builtin_amdgcn_exp2f(sc[kt2][2] - mnew);
      float p3 = __builtin_amdgcn_exp2f(sc[kt2][3] - mnew);
      rs += (p0 + p1) + (p2 + p3);
      union { uint2 u; bf16 hh[4]; } pk;
      pk.hh[0] = __float2bfloat16(p0); pk.hh[1] = __float2bfloat16(p1);
      pk.hh[2] = __float2bfloat16(p2); pk.hh[3] = __float2bfloat16(p3);
      int phys = (kt2*4 + quad) ^ swz;
      *(uint2*)&Ps[q*128 + phys*4] = pk.u;
    }
    rs += __shfl_xor(rs, 16);
    rs += __shfl_xor(rs, 32);
    l_s = l_s*alpha + rs;
    m_s = mnew;
    #pragma unroll
    for (int dt = 0; dt < 4; ++dt) acc_o[dt] = acc_o[dt] * alpha;
    // no barrier: Ps rows are wave-private; lgkmcnt orders write->read

    // ---- O^T += V^T P^T ----
    __builtin_amdgcn_s_setprio(1);
    #pragma unroll
    for (int ks2 = 0; ks2 < 4; ++ks2) {
      bf16x8 vf[4], pa;
      #pragma unroll
      for (int dt = 0; dt < 4; ++dt) {
        int n = dt*16 + l16;
        int sw = (ks2*4 + quad + n + (n >> 3)) & 15;
        vf[dt] = *(const bf16x8*)&Vt[(n*16 + sw)*8];
      }
      int phys = (ks2*8 + quad*2) ^ swz;
      pa = *(const bf16x8*)&Ps[q*128 + phys*4];
      #pragma unroll
      for (int dt = 0; dt < 4; ++dt)
        acc_o[dt] = __builtin_amdgcn_mfma_f32_16x16x32_bf16(vf[dt], pa, acc_o[dt], 0, 0, 0);
    }
    __builtin_amdgcn_s_setprio(0);
    // pin everything (PV ds_reads + their lgkm waits + MFMAs) before bar1
    __builtin_amdgcn_sched_barrier(0);
  }

  bf16* Ob = Ao + ((size_t)b*SEQ + q0)*D_MODEL + h*DHEAD;
  float inv = 1.f / l_s;
  #pragma unroll
  for (int dt = 0; dt < 4; ++dt) {
    union { uint2 u; bf16 hh[4]; } pk;
    #pragma unroll
    for (int j = 0; j < 4; ++j) pk.hh[j] = __float2bfloat16(acc_o[dt][j] * inv);
    *(uint2*)(Ob + (size_t)q*D_MODEL + dt*16 + quad*4) = pk.u;
  }
}

// ---------------------------------------------------------------------------
extern "C" void kernel_launch(void* const* d_in, const int* in_sizes, int n_in,
                              void* d_out, int out_size, void* d_ws, size_t ws_size,
                              hipStream_t stream) {
  const float* q   = (const float*)d_in[0];
  const float* k   = (const float*)d_in[1];
  const float* v   = (const float*)d_in[2];
  const float* w_q = (const float*)d_in[3];
  const float* b_q = (const float*)d_in[4];
  const float* w_k = (const float*)d_in[5];
  const float* b_k = (const float*)d_in[6];
  const float* w_v = (const float*)d_in[7];
  const float* b_v = (const float*)d_in[8];
  const float* w_o = (const float*)d_in[9];
  const float* b_o = (const float*)d_in[10];

  const size_t nbuf = (size_t)MROWS * D_MODEL;
  const size_t wbuf = (size_t)D_MODEL * D_MODEL;
  bf16* Kp  = (bf16*)d_out;                       // d_out (fp32,16.8MB) scratch
  bf16* VpT = Kp + nbuf;

  const size_t needA = 256 + (3*nbuf + 4*wbuf + nbuf) * 2;  // ~41.9 MB
  if (ws_size >= needA) {
    bf16* qc  = (bf16*)((char*)d_ws + 256);
    bf16* kc  = qc  + nbuf;
    bf16* vc  = kc  + nbuf;
    bf16* wqc = vc  + nbuf;
    bf16* wkc = wqc + wbuf;
    bf16* wvc = wkc + wbuf;
    bf16* woc = wvc + wbuf;
    bf16* Qp  = woc + wbuf;
    bf16* Ao  = Qp;                   // alias: block-local slices only

    convert7<<<dim3(512,7), 256, 0, stream>>>(q, k, v, w_q, w_k, w_v, w_o,
                                              qc, kc, vc, wqc, wkc, wvc, woc);
    gemm3_dma<<<dim3(8,32,3), 512, 0, stream>>>(qc, kc, vc, wqc, wkc, wvc,
                                                b_q, b_k, b_v, Qp, Kp, VpT);
    attn_fused<<<dim3(16,16,2), 512, 0, stream>>>(Qp, Kp, VpT, Ao);
    gemm_out_dma<<<dim3(16,32), 256, 0, stream>>>(Ao, woc, b_o, (float*)d_out);
  } else {
    bf16* Qp = (bf16*)((char*)d_ws + 256);
    bf16* Ao = Qp;
    gemm3_fused<<<dim3(8,32,3), 256, 0, stream>>>(q, k, v, w_q, w_k, w_v,
                                                  b_q, b_k, b_v, Qp, Kp, VpT);
    attn_fused<<<dim3(16,16,2), 512, 0, stream>>>(Qp, Kp, VpT, Ao);
    gemm_out_fused<<<dim3(16,32), 256, 0, stream>>>(Ao, w_o, b_o, (float*)d_out);
  }
}